// Round 1
// baseline (1605.475 us; speedup 1.0000x reference)
//
#include <hip/hip_runtime.h>
#include <hip/hip_bf16.h>
#include <math.h>

#define N_NODES 100000
#define N_EDGES 800000
#define DIM_IN  128
#define DIM_HID 64
#define DIM_OUT 40
// 20 solve iters (reference hits MAX_ITER or is within TOL) + 5 phantom steps.
// Step 1 (u0=0 -> u1 = gamma*relu(b)) is fused into enc_bias, so 24 spmm launches.
#define SPMM_ITERS 24

__device__ __forceinline__ float sigmf(float v){ return 1.0f/(1.0f+expf(-v)); }

// sc[0]=sigmoid(beta_p), sc[1]=sigmoid(gamma_p)
__global__ void prep_scalars(const float* __restrict__ bp, const float* __restrict__ gp,
                             float* __restrict__ sc){
  if(threadIdx.x==0){ sc[0]=sigmf(bp[0]); sc[1]=sigmf(gp[0]); }
}

// -------- CSR build (group edges by dst) --------
__global__ void hist_kernel(const int* __restrict__ ei, int* __restrict__ deg){
  int e = blockIdx.x*256 + threadIdx.x;
  if(e < N_EDGES){
    int d = ei[N_EDGES + e];
    atomicAdd(&deg[d], 1);
  }
}

__global__ void scan1(const int* __restrict__ deg, int* __restrict__ excl,
                      int* __restrict__ bsum){
  __shared__ int tmp[2][1024];
  int t = threadIdx.x;
  int g = blockIdx.x*1024 + t;
  int v = (g < N_NODES) ? deg[g] : 0;
  tmp[0][t] = v;
  __syncthreads();
  int pi = 0;
  for(int off=1; off<1024; off<<=1){
    int po = pi^1;
    int val = tmp[pi][t];
    if(t >= off) val += tmp[pi][t-off];
    tmp[po][t] = val;
    __syncthreads();
    pi = po;
  }
  int incl = tmp[pi][t];
  if(g < N_NODES) excl[g] = incl - v;
  if(t == 1023) bsum[blockIdx.x] = incl;
}

__global__ void scan2(int* __restrict__ bsum, int nb){
  __shared__ int tmp[2][128];
  int t = threadIdx.x;
  int v = (t < nb) ? bsum[t] : 0;
  tmp[0][t] = v;
  __syncthreads();
  int pi = 0;
  for(int off=1; off<128; off<<=1){
    int po = pi^1;
    int val = tmp[pi][t];
    if(t >= off) val += tmp[pi][t-off];
    tmp[po][t] = val;
    __syncthreads();
    pi = po;
  }
  int incl = tmp[pi][t];
  if(t < nb) bsum[t] = incl - v;   // exclusive scan of block sums
}

__global__ void scan3(int* __restrict__ rowptr, const int* __restrict__ bsum){
  int g = blockIdx.x*256 + threadIdx.x;
  if(g < N_NODES) rowptr[g] += bsum[g>>10];
  if(g == 0) rowptr[N_NODES] = N_EDGES;
}

__global__ void scatter_kernel(const int* __restrict__ ei, const float* __restrict__ ew,
                               const int* __restrict__ rowptr, int* __restrict__ fill,
                               int* __restrict__ col, float* __restrict__ val){
  int e = blockIdx.x*256 + threadIdx.x;
  if(e < N_EDGES){
    int s = ei[e];
    int d = ei[N_EDGES + e];
    int p = rowptr[d] + atomicAdd(&fill[d], 1);
    col[p] = s;
    val[p] = ew[e];
  }
}

// -------- Wc = W_bias @ W_enc  [64,128], bc = W_bias @ b_enc [64] --------
__global__ void wcomb_kernel(const float* __restrict__ W_bias, const float* __restrict__ W_enc,
                             const float* __restrict__ b_enc, float* __restrict__ Wc,
                             float* __restrict__ bc){
  int idx = blockIdx.x*256 + threadIdx.x;
  if(idx < DIM_HID*DIM_IN){
    int i = idx >> 7;          // hid row
    int k = idx & 127;         // in col
    float a = 0.f;
    #pragma unroll 8
    for(int j=0;j<DIM_HID;++j) a = fmaf(W_bias[i*DIM_HID+j], W_enc[j*DIM_IN+k], a);
    Wc[idx] = a;
  } else if(idx < DIM_HID*DIM_IN + DIM_HID){
    int i = idx - DIM_HID*DIM_IN;
    float a = 0.f;
    #pragma unroll 8
    for(int j=0;j<DIM_HID;++j) a = fmaf(W_bias[i*DIM_HID+j], b_enc[j], a);
    bc[i] = a;
  }
}

// -------- b = x @ Wc^T + bc ; u1 = gamma*relu(b)  (first fixed-point step fused) --------
// 256 threads = 4 waves; each wave handles 4 rows sequentially; 16 rows/block.
__global__ __launch_bounds__(256) void enc_bias_kernel(
    const float* __restrict__ x, const float* __restrict__ Wc, const float* __restrict__ bc,
    const float* __restrict__ sc, float* __restrict__ b, float* __restrict__ u1){
  __shared__ float WcT[128*65];   // [k][f], padded stride 65 -> conflict-free
  __shared__ float xs[4][128];
  __shared__ float bcs[64];
  int t = threadIdx.x;
  for(int idx=t; idx<DIM_HID*DIM_IN; idx+=256){
    int fr = idx >> 7;      // output feature
    int k  = idx & 127;     // input dim
    WcT[k*65 + fr] = Wc[idx];     // coalesced global read
  }
  if(t < 64) bcs[t] = bc[t];
  __syncthreads();
  float gamma = sc[1];
  int w = t >> 6, f = t & 63;
  int base = blockIdx.x*16 + w*4;
  for(int rr=0; rr<4; ++rr){
    int row = base + rr;
    if(row >= N_NODES) break;
    xs[w][f]      = x[(size_t)row*128 + f];
    xs[w][64 + f] = x[(size_t)row*128 + 64 + f];
    float acc = bcs[f];
    #pragma unroll 8
    for(int k=0;k<128;++k){
      acc = fmaf(xs[w][k], WcT[k*65 + f], acc);
    }
    size_t o = (size_t)row*64 + f;
    b[o]  = acc;
    u1[o] = gamma * fmaxf(acc, 0.f);
  }
}

// -------- fused SpMM + pointwise update: un = g*relu(beta*Pu + b) + (1-g)*u --------
// one wave per dst row, lane f owns feature f; coalesced 256B gather per edge.
__global__ __launch_bounds__(256) void spmm_update(
    const int* __restrict__ rowptr, const int* __restrict__ col, const float* __restrict__ val,
    const float* __restrict__ b, const float* __restrict__ sc,
    const float* __restrict__ u, float* __restrict__ un){
  int w = threadIdx.x >> 6, f = threadIdx.x & 63;
  int row = blockIdx.x*4 + w;
  if(row >= N_NODES) return;
  float beta = sc[0], gamma = sc[1];
  int s0 = rowptr[row], s1 = rowptr[row+1];
  float acc0 = 0.f, acc1 = 0.f;
  int j = s0;
  for(; j+3 < s1; j+=4){
    int   c0 = col[j],   c1 = col[j+1], c2 = col[j+2], c3 = col[j+3];
    float w0 = val[j],   w1 = val[j+1], w2 = val[j+2], w3 = val[j+3];
    acc0 = fmaf(w0, u[(size_t)c0*64 + f], acc0);
    acc1 = fmaf(w1, u[(size_t)c1*64 + f], acc1);
    acc0 = fmaf(w2, u[(size_t)c2*64 + f], acc0);
    acc1 = fmaf(w3, u[(size_t)c3*64 + f], acc1);
  }
  for(; j < s1; ++j){
    acc0 = fmaf(val[j], u[(size_t)col[j]*64 + f], acc0);
  }
  float acc = acc0 + acc1;
  size_t idx = (size_t)row*64 + f;
  un[idx] = gamma * fmaxf(fmaf(beta, acc, b[idx]), 0.f) + (1.f - gamma) * u[idx];
}

// -------- out = relu(u) @ W_dec^T --------
__global__ __launch_bounds__(256) void dec_kernel(
    const float* __restrict__ u, const float* __restrict__ Wd, float* __restrict__ out){
  __shared__ float WdT[DIM_HID*DIM_OUT];  // [f][o]
  __shared__ float us[4][64];
  int t = threadIdx.x;
  for(int idx=t; idx<DIM_HID*DIM_OUT; idx+=256){
    int fdim = idx / DIM_OUT;
    int o    = idx - fdim*DIM_OUT;
    WdT[idx] = Wd[o*DIM_HID + fdim];
  }
  __syncthreads();
  int w = t >> 6, lane = t & 63;
  int row = blockIdx.x*4 + w;
  if(row >= N_NODES) return;
  us[w][lane] = fmaxf(u[(size_t)row*64 + lane], 0.f);
  if(lane < DIM_OUT){
    float acc = 0.f;
    #pragma unroll 8
    for(int f=0; f<DIM_HID; ++f) acc = fmaf(us[w][f], WdT[f*DIM_OUT + lane], acc);
    out[(size_t)row*DIM_OUT + lane] = acc;
  }
}

extern "C" void kernel_launch(void* const* d_in, const int* in_sizes, int n_in,
                              void* d_out, int out_size, void* d_ws, size_t ws_size,
                              hipStream_t stream){
  const float* x       = (const float*)d_in[0];
  const int*   ei      = (const int*)  d_in[1];   // [2,E] (harness: integer -> int32)
  const float* ew      = (const float*)d_in[2];
  const float* W_enc   = (const float*)d_in[3];
  const float* b_enc   = (const float*)d_in[4];
  const float* W_bias  = (const float*)d_in[5];
  const float* W_dec   = (const float*)d_in[6];
  const float* beta_p  = (const float*)d_in[7];
  const float* gamma_p = (const float*)d_in[8];
  float* out = (float*)d_out;

  char* ws = (char*)d_ws;
  size_t off = 0;
  auto alloc = [&](size_t bytes)->void*{
    void* p = ws + off;
    off += (bytes + 255) & ~(size_t)255;
    return p;
  };
  float* b      = (float*)alloc((size_t)N_NODES*64*4);
  float* uA     = (float*)alloc((size_t)N_NODES*64*4);
  float* uB     = (float*)alloc((size_t)N_NODES*64*4);
  float* Wc     = (float*)alloc((size_t)DIM_HID*DIM_IN*4);
  float* bc     = (float*)alloc(64*4);
  float* sc     = (float*)alloc(2*4);
  int*   rowptr = (int*)  alloc((size_t)(N_NODES+1)*4);
  int*   degf   = (int*)  alloc((size_t)N_NODES*4);
  int*   bsum   = (int*)  alloc(128*4);
  int*   col    = (int*)  alloc((size_t)N_EDGES*4);
  float* val    = (float*)alloc((size_t)N_EDGES*4);

  prep_scalars<<<1, 64, 0, stream>>>(beta_p, gamma_p, sc);

  // CSR build (same every call; inputs restored before each timed launch)
  hipMemsetAsync(degf, 0, (size_t)N_NODES*4, stream);
  hist_kernel<<<(N_EDGES+255)/256, 256, 0, stream>>>(ei, degf);
  int nb1 = (N_NODES + 1023)/1024;
  scan1<<<nb1, 1024, 0, stream>>>(degf, rowptr, bsum);
  scan2<<<1, 128, 0, stream>>>(bsum, nb1);
  scan3<<<(N_NODES+255)/256, 256, 0, stream>>>(rowptr, bsum);
  hipMemsetAsync(degf, 0, (size_t)N_NODES*4, stream);
  scatter_kernel<<<(N_EDGES+255)/256, 256, 0, stream>>>(ei, ew, rowptr, degf, col, val);

  // fused encoder: Wc = W_bias@W_enc, bc = W_bias@b_enc; b = x@Wc^T + bc; u1 = g*relu(b)
  wcomb_kernel<<<(DIM_HID*DIM_IN + DIM_HID + 255)/256, 256, 0, stream>>>(W_bias, W_enc, b_enc, Wc, bc);
  enc_bias_kernel<<<N_NODES/16, 256, 0, stream>>>(x, Wc, bc, sc, b, uA);

  // 24 remaining fixed-point/phantom steps (25 total applications of step())
  float* ucur = uA;
  float* unext = uB;
  for(int it=0; it<SPMM_ITERS; ++it){
    spmm_update<<<(N_NODES+3)/4, 256, 0, stream>>>(rowptr, col, val, b, sc, ucur, unext);
    float* tmp = ucur; ucur = unext; unext = tmp;
  }

  dec_kernel<<<(N_NODES+3)/4, 256, 0, stream>>>(ucur, W_dec, out);
}

// Round 2
// 1375.327 us; speedup vs baseline: 1.1673x; 1.1673x over previous
//
#include <hip/hip_runtime.h>
#include <hip/hip_bf16.h>
#include <math.h>

#define N_NODES 100000
#define N_EDGES 800000
#define DIM_IN  128
#define DIM_HID 64
#define DIM_OUT 40
// 20 solve iters (reference hits MAX_ITER / within TOL) + 5 phantom steps.
// Step 1 (u0=0 -> u1 = gamma*relu(b)) is fused into enc_bias, so 24 spmm launches.
#define SPMM_ITERS 24

__device__ __forceinline__ float sigmf(float v){ return 1.0f/(1.0f+expf(-v)); }

__global__ void prep_scalars(const float* __restrict__ bp, const float* __restrict__ gp,
                             float* __restrict__ sc){
  if(threadIdx.x==0){ sc[0]=sigmf(bp[0]); sc[1]=sigmf(gp[0]); }
}

// -------- CSR build (group edges by dst) --------
__global__ void hist_kernel(const int* __restrict__ ei, int* __restrict__ deg){
  int e = blockIdx.x*256 + threadIdx.x;
  if(e < N_EDGES){
    int d = ei[N_EDGES + e];
    atomicAdd(&deg[d], 1);
  }
}

__global__ void scan1(const int* __restrict__ deg, int* __restrict__ excl,
                      int* __restrict__ bsum){
  __shared__ int tmp[2][1024];
  int t = threadIdx.x;
  int g = blockIdx.x*1024 + t;
  int v = (g < N_NODES) ? deg[g] : 0;
  tmp[0][t] = v;
  __syncthreads();
  int pi = 0;
  for(int off=1; off<1024; off<<=1){
    int po = pi^1;
    int val = tmp[pi][t];
    if(t >= off) val += tmp[pi][t-off];
    tmp[po][t] = val;
    __syncthreads();
    pi = po;
  }
  int incl = tmp[pi][t];
  if(g < N_NODES) excl[g] = incl - v;
  if(t == 1023) bsum[blockIdx.x] = incl;
}

__global__ void scan2(int* __restrict__ bsum, int nb){
  __shared__ int tmp[2][128];
  int t = threadIdx.x;
  int v = (t < nb) ? bsum[t] : 0;
  tmp[0][t] = v;
  __syncthreads();
  int pi = 0;
  for(int off=1; off<128; off<<=1){
    int po = pi^1;
    int val = tmp[pi][t];
    if(t >= off) val += tmp[pi][t-off];
    tmp[po][t] = val;
    __syncthreads();
    pi = po;
  }
  int incl = tmp[pi][t];
  if(t < nb) bsum[t] = incl - v;
}

__global__ void scan3(int* __restrict__ rowptr, const int* __restrict__ bsum){
  int g = blockIdx.x*256 + threadIdx.x;
  if(g < N_NODES) rowptr[g] += bsum[g>>10];
  if(g == 0) rowptr[N_NODES] = N_EDGES;
}

__global__ void scatter_kernel(const int* __restrict__ ei, const float* __restrict__ ew,
                               const int* __restrict__ rowptr, int* __restrict__ fill,
                               int* __restrict__ col, float* __restrict__ val){
  int e = blockIdx.x*256 + threadIdx.x;
  if(e < N_EDGES){
    int s = ei[e];
    int d = ei[N_EDGES + e];
    int p = rowptr[d] + atomicAdd(&fill[d], 1);
    col[p] = s;
    val[p] = ew[e];
  }
}

// -------- Wc = W_bias @ W_enc  [64,128], bc = W_bias @ b_enc [64] --------
__global__ void wcomb_kernel(const float* __restrict__ W_bias, const float* __restrict__ W_enc,
                             const float* __restrict__ b_enc, float* __restrict__ Wc,
                             float* __restrict__ bc){
  int idx = blockIdx.x*256 + threadIdx.x;
  if(idx < DIM_HID*DIM_IN){
    int i = idx >> 7;
    int k = idx & 127;
    float a = 0.f;
    #pragma unroll 8
    for(int j=0;j<DIM_HID;++j) a = fmaf(W_bias[i*DIM_HID+j], W_enc[j*DIM_IN+k], a);
    Wc[idx] = a;
  } else if(idx < DIM_HID*DIM_IN + DIM_HID){
    int i = idx - DIM_HID*DIM_IN;
    float a = 0.f;
    #pragma unroll 8
    for(int j=0;j<DIM_HID;++j) a = fmaf(W_bias[i*DIM_HID+j], b_enc[j], a);
    bc[i] = a;
  }
}

// -------- b = x @ Wc^T + bc ; u1 = gamma*relu(b) --------
// thread-per-row: x row in VGPRs (32 float4), Wc read at wave-uniform
// addresses -> s_load; inner loop = pure v_fmac with SGPR operand.
__global__ __launch_bounds__(256) void enc_bias_kernel(
    const float* __restrict__ x, const float* __restrict__ Wc, const float* __restrict__ bc,
    const float* __restrict__ sc, float* __restrict__ b, float* __restrict__ u1){
  int row = blockIdx.x*256 + threadIdx.x;
  if(row >= N_NODES) return;
  float gamma = sc[1];
  float4 xv[32];
  const float4* xp = (const float4*)(x + (size_t)row*128);
  #pragma unroll
  for(int i=0;i<32;++i) xv[i] = xp[i];
  // two output features at a time -> 2 independent fma chains
  for(int f=0; f<DIM_HID; f+=2){
    const float* w0 = Wc + (size_t)f*128;
    const float* w1 = w0 + 128;
    float a0 = bc[f], a1 = bc[f+1];
    #pragma unroll
    for(int k=0;k<128;k+=4){
      float4 xk = xv[k>>2];
      a0 = fmaf(xk.x, w0[k],   a0);  a1 = fmaf(xk.x, w1[k],   a1);
      a0 = fmaf(xk.y, w0[k+1], a0);  a1 = fmaf(xk.y, w1[k+1], a1);
      a0 = fmaf(xk.z, w0[k+2], a0);  a1 = fmaf(xk.z, w1[k+2], a1);
      a0 = fmaf(xk.w, w0[k+3], a0);  a1 = fmaf(xk.w, w1[k+3], a1);
    }
    size_t o = (size_t)row*64 + f;
    float2 bb; bb.x = a0; bb.y = a1;
    *(float2*)(b + o) = bb;
    float2 uu; uu.x = gamma*fmaxf(a0,0.f); uu.y = gamma*fmaxf(a1,0.f);
    *(float2*)(u1 + o) = uu;
  }
}

// -------- fused SpMM + pointwise: un = g*relu(beta*Pu + b) + (1-g)*u --------
// one wave per dst row (readfirstlane -> rowptr/col/val via s_load).
// feature dim packed float2: lanes 0-31 edge j, lanes 32-63 edge j+1;
// one global_load_dwordx2 covers 2 edges (512B). Halves merged by shfl_xor 32.
__global__ __launch_bounds__(256) void spmm_update(
    const int* __restrict__ rowptr, const int* __restrict__ col, const float* __restrict__ val,
    const float* __restrict__ b, const float* __restrict__ sc,
    const float* __restrict__ u, float* __restrict__ un){
  int lane = threadIdx.x & 63;
  int w    = threadIdx.x >> 6;
  int row  = __builtin_amdgcn_readfirstlane(blockIdx.x*4 + w);
  if(row >= N_NODES) return;
  int half = lane >> 5;
  int l    = lane & 31;

  float beta = sc[0], gamma = sc[1];
  size_t eidx = (size_t)row*64 + 2*l;
  float2 b2 = *(const float2*)(b + eidx);   // prefetch early
  float2 u2 = *(const float2*)(u + eidx);

  int s0 = rowptr[row], s1 = rowptr[row+1];
  float ax0=0.f, ay0=0.f, ax1=0.f, ay1=0.f;
  int j = s0;
  for(; j+3 < s1; j += 4){
    int   c0=col[j], c1=col[j+1], c2=col[j+2], c3=col[j+3];
    float w0=val[j], w1=val[j+1], w2=val[j+2], w3=val[j+3];
    int   ca = half ? c1 : c0;  float wa = half ? w1 : w0;
    int   cb = half ? c3 : c2;  float wb = half ? w3 : w2;
    float2 va = *(const float2*)(u + (size_t)ca*64 + 2*l);
    float2 vb = *(const float2*)(u + (size_t)cb*64 + 2*l);
    ax0 = fmaf(wa, va.x, ax0);  ay0 = fmaf(wa, va.y, ay0);
    ax1 = fmaf(wb, vb.x, ax1);  ay1 = fmaf(wb, vb.y, ay1);
  }
  for(; j+1 < s1; j += 2){
    int   c0=col[j], c1=col[j+1];
    float w0=val[j], w1=val[j+1];
    int   ca = half ? c1 : c0;  float wa = half ? w1 : w0;
    float2 va = *(const float2*)(u + (size_t)ca*64 + 2*l);
    ax0 = fmaf(wa, va.x, ax0);  ay0 = fmaf(wa, va.y, ay0);
  }
  if(j < s1){
    int   ca = col[j];
    float wa = half ? 0.f : val[j];
    float2 va = *(const float2*)(u + (size_t)ca*64 + 2*l);
    ax0 = fmaf(wa, va.x, ax0);  ay0 = fmaf(wa, va.y, ay0);
  }
  float ax = ax0 + ax1;
  float ay = ay0 + ay1;
  ax += __shfl_xor(ax, 32, 64);
  ay += __shfl_xor(ay, 32, 64);
  if(half == 0){
    float2 o;
    o.x = gamma*fmaxf(fmaf(beta, ax, b2.x), 0.f) + (1.f-gamma)*u2.x;
    o.y = gamma*fmaxf(fmaf(beta, ay, b2.y), 0.f) + (1.f-gamma)*u2.y;
    *(float2*)(un + eidx) = o;
  }
}

// -------- out = relu(u) @ W_dec^T --------
// thread-per-row: relu(u row) in VGPRs (16 float4), Wd via s_load,
// 4 outputs at a time -> 4 independent chains, float4 store.
__global__ __launch_bounds__(256) void dec_kernel(
    const float* __restrict__ u, const float* __restrict__ Wd, float* __restrict__ out){
  int row = blockIdx.x*256 + threadIdx.x;
  if(row >= N_NODES) return;
  float4 uv[16];
  const float4* up = (const float4*)(u + (size_t)row*64);
  #pragma unroll
  for(int i=0;i<16;++i){
    float4 v = up[i];
    v.x = fmaxf(v.x, 0.f); v.y = fmaxf(v.y, 0.f);
    v.z = fmaxf(v.z, 0.f); v.w = fmaxf(v.w, 0.f);
    uv[i] = v;
  }
  for(int ob=0; ob<DIM_OUT; ob+=4){
    const float* wd0 = Wd + (size_t)ob*64;
    const float* wd1 = wd0 + 64;
    const float* wd2 = wd0 + 128;
    const float* wd3 = wd0 + 192;
    float a0=0.f, a1=0.f, a2=0.f, a3=0.f;
    #pragma unroll
    for(int f=0; f<64; f+=4){
      float4 uk = uv[f>>2];
      a0 = fmaf(uk.x, wd0[f],   a0);  a1 = fmaf(uk.x, wd1[f],   a1);
      a2 = fmaf(uk.x, wd2[f],   a2);  a3 = fmaf(uk.x, wd3[f],   a3);
      a0 = fmaf(uk.y, wd0[f+1], a0);  a1 = fmaf(uk.y, wd1[f+1], a1);
      a2 = fmaf(uk.y, wd2[f+1], a2);  a3 = fmaf(uk.y, wd3[f+1], a3);
      a0 = fmaf(uk.z, wd0[f+2], a0);  a1 = fmaf(uk.z, wd1[f+2], a1);
      a2 = fmaf(uk.z, wd2[f+2], a2);  a3 = fmaf(uk.z, wd3[f+2], a3);
      a0 = fmaf(uk.w, wd0[f+3], a0);  a1 = fmaf(uk.w, wd1[f+3], a1);
      a2 = fmaf(uk.w, wd2[f+3], a2);  a3 = fmaf(uk.w, wd3[f+3], a3);
    }
    float4 o; o.x=a0; o.y=a1; o.z=a2; o.w=a3;
    *(float4*)(out + (size_t)row*DIM_OUT + ob) = o;
  }
}

extern "C" void kernel_launch(void* const* d_in, const int* in_sizes, int n_in,
                              void* d_out, int out_size, void* d_ws, size_t ws_size,
                              hipStream_t stream){
  const float* x       = (const float*)d_in[0];
  const int*   ei      = (const int*)  d_in[1];
  const float* ew      = (const float*)d_in[2];
  const float* W_enc   = (const float*)d_in[3];
  const float* b_enc   = (const float*)d_in[4];
  const float* W_bias  = (const float*)d_in[5];
  const float* W_dec   = (const float*)d_in[6];
  const float* beta_p  = (const float*)d_in[7];
  const float* gamma_p = (const float*)d_in[8];
  float* out = (float*)d_out;

  char* ws = (char*)d_ws;
  size_t off = 0;
  auto alloc = [&](size_t bytes)->void*{
    void* p = ws + off;
    off += (bytes + 255) & ~(size_t)255;
    return p;
  };
  float* b      = (float*)alloc((size_t)N_NODES*64*4);
  float* uA     = (float*)alloc((size_t)N_NODES*64*4);
  float* uB     = (float*)alloc((size_t)N_NODES*64*4);
  float* Wc     = (float*)alloc((size_t)DIM_HID*DIM_IN*4);
  float* bc     = (float*)alloc(64*4);
  float* sc     = (float*)alloc(2*4);
  int*   rowptr = (int*)  alloc((size_t)(N_NODES+1)*4);
  int*   degf   = (int*)  alloc((size_t)N_NODES*4);
  int*   bsum   = (int*)  alloc(128*4);
  int*   col    = (int*)  alloc((size_t)N_EDGES*4);
  float* val    = (float*)alloc((size_t)N_EDGES*4);

  prep_scalars<<<1, 64, 0, stream>>>(beta_p, gamma_p, sc);

  hipMemsetAsync(degf, 0, (size_t)N_NODES*4, stream);
  hist_kernel<<<(N_EDGES+255)/256, 256, 0, stream>>>(ei, degf);
  int nb1 = (N_NODES + 1023)/1024;
  scan1<<<nb1, 1024, 0, stream>>>(degf, rowptr, bsum);
  scan2<<<1, 128, 0, stream>>>(bsum, nb1);
  scan3<<<(N_NODES+255)/256, 256, 0, stream>>>(rowptr, bsum);
  hipMemsetAsync(degf, 0, (size_t)N_NODES*4, stream);
  scatter_kernel<<<(N_EDGES+255)/256, 256, 0, stream>>>(ei, ew, rowptr, degf, col, val);

  wcomb_kernel<<<(DIM_HID*DIM_IN + DIM_HID + 255)/256, 256, 0, stream>>>(W_bias, W_enc, b_enc, Wc, bc);
  enc_bias_kernel<<<(N_NODES+255)/256, 256, 0, stream>>>(x, Wc, bc, sc, b, uA);

  float* ucur = uA;
  float* unext = uB;
  for(int it=0; it<SPMM_ITERS; ++it){
    spmm_update<<<(N_NODES+3)/4, 256, 0, stream>>>(rowptr, col, val, b, sc, ucur, unext);
    float* tmp = ucur; ucur = unext; unext = tmp;
  }

  dec_kernel<<<(N_NODES+255)/256, 256, 0, stream>>>(ucur, W_dec, out);
}